// Round 2
// baseline (541.125 us; speedup 1.0000x reference)
//
#include <hip/hip_runtime.h>
#include <hip/hip_bf16.h>

#define PDIM 4096
#define PPN ((size_t)PDIM * (size_t)PDIM)

typedef __attribute__((ext_vector_type(8))) short bf16x8;
typedef __attribute__((ext_vector_type(4))) float floatx4;
typedef __attribute__((ext_vector_type(8))) int int8v;

__device__ __forceinline__ void load_lds16(const void* g, void* l) {
  __builtin_amdgcn_global_load_lds(
      (const __attribute__((address_space(1))) void*)g,
      (__attribute__((address_space(3))) void*)l, 16, 0, 0);
}

__device__ __forceinline__ unsigned short bf16bits(float f) {
  __hip_bfloat16 h = __float2bfloat16(f);
  return *(unsigned short*)&h;
}

__device__ __forceinline__ unsigned char fp8byte(float v) {
  return (unsigned char)(__builtin_amdgcn_cvt_pk_fp8_f32(v, v, 0, false) & 0xff);
}
__device__ __forceinline__ unsigned int fp8x4(float a, float b, float c, float d) {
  int v = __builtin_amdgcn_cvt_pk_fp8_f32(a, b, 0, false);
  v = __builtin_amdgcn_cvt_pk_fp8_f32(c, d, v, true);
  return (unsigned int)v;
}

// ---- ||X||_F^2: grid-stride, 1 atomic per block ----
__global__ void sumsq(const float4* __restrict__ x, float* __restrict__ acc) {
  float s = 0.f;
  const size_t n4 = PPN / 4;
  for (size_t i = (size_t)blockIdx.x * 256 + threadIdx.x; i < n4;
       i += (size_t)gridDim.x * 256) {
    const float4 v = x[i];
    s += v.x * v.x + v.y * v.y + v.z * v.z + v.w * v.w;
  }
#pragma unroll
  for (int off = 32; off > 0; off >>= 1) s += __shfl_down(s, off);
  __shared__ float ws[4];
  if ((threadIdx.x & 63) == 0) ws[threadIdx.x >> 6] = s;
  __syncthreads();
  if (threadIdx.x == 0) atomicAdd(acc, ws[0] + ws[1] + ws[2] + ws[3]);
}

// ---- X: fp32 -> bf16 (normal) + fp8 e4m3 (transposed) ----
__global__ void cast_x(const float* __restrict__ src,
                       __hip_bfloat16* __restrict__ dstN,
                       unsigned char* __restrict__ dstT8) {
  __shared__ float tile[64][65];
  const int bx = blockIdx.x * 64, by = blockIdx.y * 64;
  const int tx = threadIdx.x & 15, ty = threadIdx.x >> 4;
#pragma unroll
  for (int r = 0; r < 4; ++r) {
    const int row = ty + r * 16;
    const float4 v = *(const float4*)&src[(size_t)(by + row) * PDIM + bx + tx * 4];
    tile[row][tx * 4 + 0] = v.x;
    tile[row][tx * 4 + 1] = v.y;
    tile[row][tx * 4 + 2] = v.z;
    tile[row][tx * 4 + 3] = v.w;
    ushort4 o;
    o.x = bf16bits(v.x); o.y = bf16bits(v.y); o.z = bf16bits(v.z); o.w = bf16bits(v.w);
    *(ushort4*)&dstN[(size_t)(by + row) * PDIM + bx + tx * 4] = o;
  }
  __syncthreads();
#pragma unroll
  for (int r = 0; r < 4; ++r) {
    const int i = ty + r * 16;
    *(unsigned int*)&dstT8[(size_t)(bx + i) * PDIM + by + tx * 4] =
        fp8x4(tile[tx * 4 + 0][i], tile[tx * 4 + 1][i],
              tile[tx * 4 + 2][i], tile[tx * 4 + 3][i]);
  }
}

// ---- Y: fp32 -> bf16 normal + bf16 transposed ----
__global__ void cast_y(const float* __restrict__ src,
                       __hip_bfloat16* __restrict__ dstN,
                       __hip_bfloat16* __restrict__ dstT) {
  __shared__ float tile[64][65];
  const int bx = blockIdx.x * 64, by = blockIdx.y * 64;
  const int tx = threadIdx.x & 15, ty = threadIdx.x >> 4;
#pragma unroll
  for (int r = 0; r < 4; ++r) {
    const int row = ty + r * 16;
    const float4 v = *(const float4*)&src[(size_t)(by + row) * PDIM + bx + tx * 4];
    tile[row][tx * 4 + 0] = v.x;
    tile[row][tx * 4 + 1] = v.y;
    tile[row][tx * 4 + 2] = v.z;
    tile[row][tx * 4 + 3] = v.w;
    ushort4 o;
    o.x = bf16bits(v.x); o.y = bf16bits(v.y); o.z = bf16bits(v.z); o.w = bf16bits(v.w);
    *(ushort4*)&dstN[(size_t)(by + row) * PDIM + bx + tx * 4] = o;
  }
  __syncthreads();
#pragma unroll
  for (int r = 0; r < 4; ++r) {
    const int i = ty + r * 16;
    ushort4 o;
    o.x = bf16bits(tile[tx * 4 + 0][i]);
    o.y = bf16bits(tile[tx * 4 + 1][i]);
    o.z = bf16bits(tile[tx * 4 + 2][i]);
    o.w = bf16bits(tile[tx * 4 + 3][i]);
    *(ushort4*)&dstT[(size_t)(bx + i) * PDIM + by + tx * 4] = o;
  }
}

// ---- W_beta: fp8 cast + row-sum + scale[i] = W^2/(s*W^2+1) ----
__global__ void cast_wb_rows(const float* __restrict__ Wb,
                             unsigned char* __restrict__ Wb8,
                             const float* __restrict__ sAcc,
                             float* __restrict__ scale) {
  const size_t row = blockIdx.x;
  const float4* src = (const float4*)(Wb + row * PDIM);
  unsigned int* dst = (unsigned int*)(Wb8 + row * PDIM);
  float sum = 0.f;
#pragma unroll
  for (int it = 0; it < 4; ++it) {
    const int j = threadIdx.x + it * 256;
    const float4 v = src[j];
    sum += (v.x + v.y) + (v.z + v.w);
    dst[j] = fp8x4(v.x, v.y, v.z, v.w);
  }
#pragma unroll
  for (int off = 32; off > 0; off >>= 1) sum += __shfl_down(sum, off);
  __shared__ float ws[4];
  if ((threadIdx.x & 63) == 0) ws[threadIdx.x >> 6] = sum;
  __syncthreads();
  if (threadIdx.x == 0) {
    const float W = ws[0] + ws[1] + ws[2] + ws[3];
    const float w2 = W * W;
    scale[row] = w2 / ((*sAcc) * w2 + 1.0f);
  }
}

// ---- GEMM1: 256x256 tile, BK=64, 8-wave, read-ahead 4-phase pipeline ----
// Wm = scale[i] * (Y . X^T). outF fp32, Wm8 fp8 scaled by 2^17.
// Phase p: {stage half-tile of t+2 -> MFMA quadrant (operands pre-read) ->
// tail-read next quadrant's operands}. One barrier per phase. Quadrants:
// Q1=MloNlo(afLo,bLo) Q2=MloNhi(afLo,bHi) Q3=MhiNhi(afHi,bHi) Q4=MhiNlo(afHi,bLo).
// Tail reads: P1:bHi(t) P2:afHi(t) P3:afLo(t+1) P4:bLo(t+1). Reads/phase {4,8,8,4}.
// vmcnt FIFO accounting (exact): vmcnt(10)@P3-top confirms Ah0(t+1);
// vmcnt(6)@P4-top confirms Ah1(t+1). Never drains to 0 in the loop.
// Staging lands >=1 full phase after each region's last read (no race window).
__device__ __forceinline__ void mfma_quad(floatx4 (&acc)[8][4], int mo, int no,
                                          const bf16x8 (&af)[8],
                                          const bf16x8 (&bf)[4]) {
  __builtin_amdgcn_s_setprio(1);
#pragma unroll
  for (int mi = 0; mi < 4; ++mi)
#pragma unroll
    for (int ni = 0; ni < 2; ++ni)
#pragma unroll
      for (int kk = 0; kk < 2; ++kk)
        acc[mo + mi][no + ni] = __builtin_amdgcn_mfma_f32_16x16x32_bf16(
            af[mi * 2 + kk], bf[ni * 2 + kk], acc[mo + mi][no + ni], 0, 0, 0);
  __builtin_amdgcn_s_setprio(0);
}

__device__ __forceinline__ void read_a(bf16x8 (&dst)[8], const char* base, int slot0) {
#pragma unroll
  for (int mi = 0; mi < 4; ++mi) {
    dst[mi * 2 + 0] = *(const bf16x8*)(base + mi * 2048 + slot0);
    dst[mi * 2 + 1] = *(const bf16x8*)(base + mi * 2048 + (slot0 ^ 64));
  }
}
__device__ __forceinline__ void read_b(bf16x8 (&dst)[4], const char* base, int slot0) {
#pragma unroll
  for (int ni = 0; ni < 2; ++ni) {
    dst[ni * 2 + 0] = *(const bf16x8*)(base + ni * 2048 + slot0);
    dst[ni * 2 + 1] = *(const bf16x8*)(base + ni * 2048 + (slot0 ^ 64));
  }
}

__global__ __launch_bounds__(512, 2)
void gemm_bf16_wm(const __hip_bfloat16* __restrict__ A,
                  const __hip_bfloat16* __restrict__ B,
                  const float* __restrict__ scale,
                  float* __restrict__ outF,
                  unsigned char* __restrict__ Wm8) {
  __shared__ __align__(16) char LDS[131072];

  const int tid = threadIdx.x;
  const int lane = tid & 63;
  const int wave = tid >> 6;
  const int wm = wave >> 2;  // 0..1  (M half owner)
  const int wn = wave & 3;   // 0..3  (N strip owner)

  // XCD-aware swizzle: 256 blocks, 8 XCDs -> 32 contiguous tiles per XCD.
  const int bid = blockIdx.x;
  const int swz = (bid & 7) * 32 + (bid >> 3);
  const int bx = swz & 15;
  const int by = swz >> 4;
  const size_t rowA0 = (size_t)by * 256;
  const size_t rowB0 = (size_t)bx * 256;

  // staging addressing (pre-swizzled global source, linear LDS dest)
  const int srow = tid >> 3;                        // 0..63
  const int scol = ((tid & 7) ^ (srow & 7)) << 4;   // swizzled 16B slot (bytes)
  const char* pA = (const char*)A + (rowA0 + srow) * 8192 + scol;
  const char* pB = (const char*)B + (rowB0 + srow) * 8192 + scol;
  const int ldsWav = wave * 1024;
  // global byte strides: half-tile = 128 rows = 1048576 B; 64-row step = 524288 B

  // fragment read addressing
  const int fr = lane & 15;
  const int kq = lane >> 4;
  const int slot0 = ((kq ^ (fr & 7)) << 4);
  const int aRowB = (wm * 64 + fr) * 128;
  const int bRowB = (wn * 32 + fr) * 128;

  floatx4 acc[8][4] = {};
  bf16x8 afLo[8], afHi[8], bLo[4], bHi[4];

  // ---- prologue: stage tiles 0,1 in steady-state order {Ah0,Bh0,Bh1,Ah1} ----
  {
    char* dA0 = LDS + ldsWav;
    char* dB0 = LDS + 65536 + ldsWav;
    load_lds16(pA, dA0);                         load_lds16(pA + 524288, dA0 + 8192);
    load_lds16(pB, dB0);                         load_lds16(pB + 524288, dB0 + 8192);
    load_lds16(pB + 1048576, dB0 + 16384);       load_lds16(pB + 1572864, dB0 + 24576);
    load_lds16(pA + 1048576, dA0 + 16384);       load_lds16(pA + 1572864, dA0 + 24576);
    char* dA1 = dA0 + 32768;
    char* dB1 = dB0 + 32768;
    load_lds16(pA + 128, dA1);                   load_lds16(pA + 128 + 524288, dA1 + 8192);
    load_lds16(pB + 128, dB1);                   load_lds16(pB + 128 + 524288, dB1 + 8192);
    load_lds16(pB + 128 + 1048576, dB1 + 16384); load_lds16(pB + 128 + 1572864, dB1 + 24576);
    load_lds16(pA + 128 + 1048576, dA1 + 16384); load_lds16(pA + 128 + 1572864, dA1 + 24576);
  }
  asm volatile("s_waitcnt vmcnt(8)" ::: "memory");   // tile 0 landed
  __builtin_amdgcn_s_barrier();
  // pre-read Q1(t=0) operands
  read_a(afLo, (const char*)LDS + aRowB, slot0);
  read_b(bLo, (const char*)LDS + 65536 + bRowB, slot0);
  asm volatile("s_waitcnt lgkmcnt(0)" ::: "memory"); // one-time drain before loop
  __builtin_amdgcn_s_barrier();

  // ---- main loop: 64 K-tiles of 64, 4 phases each, 1 barrier/phase ----
  for (int t = 0; t < 64; ++t) {
    const int buf = (t & 1) << 15;
    const int tS = (t + 2) & 63;                 // wraps at tail; data unused
    const char* sA = pA + (size_t)tS * 128;
    const char* sB = pB + (size_t)tS * 128;
    char* dA = LDS + buf + ldsWav;
    char* dB = LDS + 65536 + buf + ldsWav;
    const char* aRd  = LDS + buf + aRowB;
    const char* bRd  = LDS + 65536 + buf + bRowB;
    const char* aRdN = LDS + (buf ^ 32768) + aRowB;
    const char* bRdN = LDS + 65536 + (buf ^ 32768) + bRowB;

    // P1: stage Ah0(t+2); Q1 = MloNlo; tail-read bHi(t)
    load_lds16(sA, dA);
    load_lds16(sA + 524288, dA + 8192);
    mfma_quad(acc, 0, 0, afLo, bLo);
    read_b(bHi, bRd + 16384, slot0);
    __builtin_amdgcn_s_barrier();

    // P2: stage Bh0(t+2); Q2 = MloNhi; tail-read afHi(t)
    load_lds16(sB, dB);
    load_lds16(sB + 524288, dB + 8192);
    mfma_quad(acc, 0, 2, afLo, bHi);
    read_a(afHi, aRd + 16384, slot0);
    __builtin_amdgcn_s_barrier();

    // P3: vmcnt(10) confirms Ah0(t+1); stage Bh1(t+2); Q3 = MhiNhi; tail afLo(t+1)
    asm volatile("s_waitcnt vmcnt(10)" ::: "memory");
    load_lds16(sB + 1048576, dB + 16384);
    load_lds16(sB + 1572864, dB + 24576);
    mfma_quad(acc, 4, 2, afHi, bHi);
    read_a(afLo, aRdN, slot0);
    __builtin_amdgcn_s_barrier();

    // P4: vmcnt(6) confirms Ah1(t+1); stage Ah1(t+2); Q4 = MhiNlo; tail bLo(t+1)
    asm volatile("s_waitcnt vmcnt(6)" ::: "memory");
    load_lds16(sA + 1048576, dA + 16384);
    load_lds16(sA + 1572864, dA + 24576);
    mfma_quad(acc, 4, 0, afHi, bLo);
    read_b(bLo, bRdN, slot0);
    __builtin_amdgcn_s_barrier();
  }

  // ---- epilogue: scale + fp32 store + fp8(2^17) store ----
  const int lr = (lane >> 4) << 2;
  const int lc = lane & 15;
#pragma unroll
  for (int mi = 0; mi < 8; ++mi) {
    const size_t rbase = rowA0 + (size_t)(mi >> 2) * 128 + wm * 64 + (mi & 3) * 16 + lr;
#pragma unroll
    for (int r = 0; r < 4; ++r) {
      const size_t row = rbase + r;
      const float sc = scale[row];
#pragma unroll
      for (int ni = 0; ni < 4; ++ni) {
        const size_t col = rowB0 + (size_t)(ni >> 1) * 128 + wn * 32 + (ni & 1) * 16 + lc;
        const float v = sc * acc[mi][ni][r];
        outF[row * PDIM + col] = v;
        Wm8[row * PDIM + col] = fp8byte(v * 131072.f);  // 2^17 pre-scale
      }
    }
  }
}

// ---- fp8 NT GEMM, 128x128 tile, BK=128, mfma_scale 16x16x128 (unit scales) ----
// LDS slot (r, s) holds global 16B chunk (r, s ^ (r&7)) -> uniform bank load.
// MODE 1: outP = fp8(acc*2^-17 - sub)   (P^T; B operand was pre-scaled 2^17)
// MODE 2: lossAcc += sum(acc^2)
template <int MODE>
__global__ __launch_bounds__(256)
void gemm_fp8(const unsigned char* __restrict__ A,
              const unsigned char* __restrict__ B,
              const __hip_bfloat16* __restrict__ sub,
              unsigned char* __restrict__ outP,
              float* __restrict__ lossAcc) {
  __shared__ __align__(16) unsigned char As[128 * 128];
  __shared__ __align__(16) unsigned char Bs[128 * 128];

  const int tid = threadIdx.x;
  const int lane = tid & 63;
  const int wave = tid >> 6;
  const int wm = wave >> 1, wn = wave & 1;

  const size_t rowA0 = (size_t)blockIdx.y * 128;
  const size_t rowB0 = (size_t)blockIdx.x * 128;

  const unsigned char* gA[4];
  const unsigned char* gB[4];
  int ldsOff[4];
#pragma unroll
  for (int m = 0; m < 4; ++m) {
    const int ci = tid + m * 256;
    const int r = ci >> 3, s = ci & 7;
    const int cg = s ^ (r & 7);
    gA[m] = A + (rowA0 + (size_t)r) * PDIM + cg * 16;
    gB[m] = B + (rowB0 + (size_t)r) * PDIM + cg * 16;
    ldsOff[m] = m * 4096 + wave * 1024;
  }

  floatx4 acc[4][4] = {};

  const int fr = lane & 15;
  const int e = fr & 7;
  const int q2 = (lane >> 4) << 1;
  const int offLo = (q2 ^ e) << 4;
  const int offHi = ((q2 + 1) ^ e) << 4;
  const int abase = (wm * 64 + fr) * 128;
  const int bbase = (wn * 64 + fr) * 128;

  for (int kt = 0; kt < PDIM; kt += 128) {
#pragma unroll
    for (int m = 0; m < 4; ++m) load_lds16(gA[m] + kt, (char*)As + ldsOff[m]);
#pragma unroll
    for (int m = 0; m < 4; ++m) load_lds16(gB[m] + kt, (char*)Bs + ldsOff[m]);
    __syncthreads();

    union { int8v v; int4 h[2]; } af[4], bg[4];
#pragma unroll
    for (int mi = 0; mi < 4; ++mi) {
      af[mi].h[0] = *(const int4*)(As + abase + mi * 2048 + offLo);
      af[mi].h[1] = *(const int4*)(As + abase + mi * 2048 + offHi);
    }
#pragma unroll
    for (int ni = 0; ni < 4; ++ni) {
      bg[ni].h[0] = *(const int4*)(Bs + bbase + ni * 2048 + offLo);
      bg[ni].h[1] = *(const int4*)(Bs + bbase + ni * 2048 + offHi);
    }
#pragma unroll
    for (int mi = 0; mi < 4; ++mi)
#pragma unroll
      for (int ni = 0; ni < 4; ++ni)
        acc[mi][ni] = __builtin_amdgcn_mfma_scale_f32_16x16x128_f8f6f4(
            af[mi].v, bg[ni].v, acc[mi][ni],
            0 /*fp8*/, 0 /*fp8*/, 0, 0x7F7F7F7F, 0, 0x7F7F7F7F);
    __syncthreads();
  }

  const size_t row0 = rowA0 + wm * 64;
  const size_t col0 = rowB0 + wn * 64;
  const int lr = (lane >> 4) << 2;
  const int lc = lane & 15;

  if constexpr (MODE == 2) {
    float tot = 0.f;
#pragma unroll
    for (int mi = 0; mi < 4; ++mi)
#pragma unroll
      for (int ni = 0; ni < 4; ++ni)
#pragma unroll
        for (int r = 0; r < 4; ++r) tot += acc[mi][ni][r] * acc[mi][ni][r];
#pragma unroll
    for (int off = 32; off > 0; off >>= 1) tot += __shfl_down(tot, off);
    __shared__ float ws[4];
    if (lane == 0) ws[wave] = tot;
    __syncthreads();
    if (tid == 0) atomicAdd(lossAcc, ws[0] + ws[1] + ws[2] + ws[3]);
  } else {
    constexpr float INV = 1.f / 131072.f;
#pragma unroll
    for (int mi = 0; mi < 4; ++mi) {
#pragma unroll
      for (int r = 0; r < 4; ++r) {
        const size_t row = row0 + mi * 16 + lr + r;
#pragma unroll
        for (int ni = 0; ni < 4; ++ni) {
          const size_t col = col0 + ni * 16 + lc;
          const float v = acc[mi][ni][r] * INV - __bfloat162float(sub[row * PDIM + col]);
          outP[row * PDIM + col] = fp8byte(v);
        }
      }
    }
  }
}

__global__ void finalize(float* __restrict__ out, const float* __restrict__ acc) {
  if (threadIdx.x == 0) out[0] = sqrtf(*acc);
}

extern "C" void kernel_launch(void* const* d_in, const int* in_sizes, int n_in,
                              void* d_out, int out_size, void* d_ws, size_t ws_size,
                              hipStream_t stream) {
  const float* X  = (const float*)d_in[0];
  const float* Y  = (const float*)d_in[1];
  const float* Wb = (const float*)d_in[2];
  float* out = (float*)d_out;  // [0]=loss, [1..]=W_matrix (fp32)

  // workspace: 3x bf16 (32MB) + 4x fp8 (16MB) = 160MB + small
  __hip_bfloat16* Xb   = (__hip_bfloat16*)d_ws;           // X bf16   (GEMM1 B)
  __hip_bfloat16* Yb   = Xb + PPN;                        // Y bf16   (GEMM1 A)
  __hip_bfloat16* YbT  = Yb + PPN;                        // Y^T bf16 (GEMM2 epi)
  unsigned char*  XT8  = (unsigned char*)(YbT + PPN);     // X^T fp8  (GEMM2 A)
  unsigned char*  Wm8  = XT8 + PPN;                       // Wm*2^17 fp8 (GEMM2 B)
  unsigned char*  Wb8  = Wm8 + PPN;                       // W_beta fp8 (GEMM3 B)
  unsigned char*  PT8  = Wb8 + PPN;                       // P^T fp8  (GEMM3 A)
  float* scale   = (float*)(PT8 + PPN);                   // [4096]
  float* sAcc    = scale + PDIM;
  float* lossAcc = sAcc + 1;

  hipMemsetAsync(sAcc, 0, 2 * sizeof(float), stream);

  sumsq<<<1024, 256, 0, stream>>>((const float4*)X, sAcc);

  dim3 cgrid(PDIM / 64, PDIM / 64);
  cast_x<<<cgrid, 256, 0, stream>>>(X, Xb, XT8);
  cast_y<<<cgrid, 256, 0, stream>>>(Y, Yb, YbT);
  cast_wb_rows<<<PDIM, 256, 0, stream>>>(Wb, Wb8, sAcc, scale);

  // GEMM1 (bf16, 256^2 read-ahead pipeline): Wm = scale[i]*Y.X^T -> out+1, Wm8
  gemm_bf16_wm<<<dim3(256), 512, 0, stream>>>(Yb, Xb, scale, out + 1, Wm8);

  dim3 ggrid(PDIM / 128, PDIM / 128);
  // GEMM2 (fp8): PT[b,a] = (XT.Wm8^T)*2^-17 - YT -> PT8
  gemm_fp8<1><<<ggrid, 256, 0, stream>>>(XT8, Wm8, YbT, PT8, nullptr);
  // GEMM3 (fp8): lossAcc += ||Wb.P||_F^2
  gemm_fp8<2><<<ggrid, 256, 0, stream>>>(PT8, Wb8, nullptr, nullptr, lossAcc);

  finalize<<<1, 1, 0, stream>>>(out, lossAcc);
}

// Round 3
// 520.588 us; speedup vs baseline: 1.0394x; 1.0394x over previous
//
#include <hip/hip_runtime.h>
#include <hip/hip_bf16.h>

#define PDIM 4096
#define PPN ((size_t)PDIM * (size_t)PDIM)

typedef __attribute__((ext_vector_type(8))) short bf16x8;
typedef __attribute__((ext_vector_type(4))) float floatx4;
typedef __attribute__((ext_vector_type(8))) int int8v;

__device__ __forceinline__ void load_lds16(const void* g, void* l) {
  __builtin_amdgcn_global_load_lds(
      (const __attribute__((address_space(1))) void*)g,
      (__attribute__((address_space(3))) void*)l, 16, 0, 0);
}

__device__ __forceinline__ unsigned short bf16bits(float f) {
  __hip_bfloat16 h = __float2bfloat16(f);
  return *(unsigned short*)&h;
}

__device__ __forceinline__ unsigned char fp8byte(float v) {
  return (unsigned char)(__builtin_amdgcn_cvt_pk_fp8_f32(v, v, 0, false) & 0xff);
}
__device__ __forceinline__ unsigned int fp8x4(float a, float b, float c, float d) {
  int v = __builtin_amdgcn_cvt_pk_fp8_f32(a, b, 0, false);
  v = __builtin_amdgcn_cvt_pk_fp8_f32(c, d, v, true);
  return (unsigned int)v;
}

// ---- ||X||_F^2: grid-stride, 1 atomic per block ----
__global__ void sumsq(const float4* __restrict__ x, float* __restrict__ acc) {
  float s = 0.f;
  const size_t n4 = PPN / 4;
  for (size_t i = (size_t)blockIdx.x * 256 + threadIdx.x; i < n4;
       i += (size_t)gridDim.x * 256) {
    const float4 v = x[i];
    s += v.x * v.x + v.y * v.y + v.z * v.z + v.w * v.w;
  }
#pragma unroll
  for (int off = 32; off > 0; off >>= 1) s += __shfl_down(s, off);
  __shared__ float ws[4];
  if ((threadIdx.x & 63) == 0) ws[threadIdx.x >> 6] = s;
  __syncthreads();
  if (threadIdx.x == 0) atomicAdd(acc, ws[0] + ws[1] + ws[2] + ws[3]);
}

// ---- X: fp32 -> bf16 (normal) + fp8 e4m3 (transposed) ----
__global__ void cast_x(const float* __restrict__ src,
                       __hip_bfloat16* __restrict__ dstN,
                       unsigned char* __restrict__ dstT8) {
  __shared__ float tile[64][65];
  const int bx = blockIdx.x * 64, by = blockIdx.y * 64;
  const int tx = threadIdx.x & 15, ty = threadIdx.x >> 4;
#pragma unroll
  for (int r = 0; r < 4; ++r) {
    const int row = ty + r * 16;
    const float4 v = *(const float4*)&src[(size_t)(by + row) * PDIM + bx + tx * 4];
    tile[row][tx * 4 + 0] = v.x;
    tile[row][tx * 4 + 1] = v.y;
    tile[row][tx * 4 + 2] = v.z;
    tile[row][tx * 4 + 3] = v.w;
    ushort4 o;
    o.x = bf16bits(v.x); o.y = bf16bits(v.y); o.z = bf16bits(v.z); o.w = bf16bits(v.w);
    *(ushort4*)&dstN[(size_t)(by + row) * PDIM + bx + tx * 4] = o;
  }
  __syncthreads();
#pragma unroll
  for (int r = 0; r < 4; ++r) {
    const int i = ty + r * 16;
    *(unsigned int*)&dstT8[(size_t)(bx + i) * PDIM + by + tx * 4] =
        fp8x4(tile[tx * 4 + 0][i], tile[tx * 4 + 1][i],
              tile[tx * 4 + 2][i], tile[tx * 4 + 3][i]);
  }
}

// ---- Y: fp32 -> bf16 normal + bf16 transposed ----
__global__ void cast_y(const float* __restrict__ src,
                       __hip_bfloat16* __restrict__ dstN,
                       __hip_bfloat16* __restrict__ dstT) {
  __shared__ float tile[64][65];
  const int bx = blockIdx.x * 64, by = blockIdx.y * 64;
  const int tx = threadIdx.x & 15, ty = threadIdx.x >> 4;
#pragma unroll
  for (int r = 0; r < 4; ++r) {
    const int row = ty + r * 16;
    const float4 v = *(const float4*)&src[(size_t)(by + row) * PDIM + bx + tx * 4];
    tile[row][tx * 4 + 0] = v.x;
    tile[row][tx * 4 + 1] = v.y;
    tile[row][tx * 4 + 2] = v.z;
    tile[row][tx * 4 + 3] = v.w;
    ushort4 o;
    o.x = bf16bits(v.x); o.y = bf16bits(v.y); o.z = bf16bits(v.z); o.w = bf16bits(v.w);
    *(ushort4*)&dstN[(size_t)(by + row) * PDIM + bx + tx * 4] = o;
  }
  __syncthreads();
#pragma unroll
  for (int r = 0; r < 4; ++r) {
    const int i = ty + r * 16;
    ushort4 o;
    o.x = bf16bits(tile[tx * 4 + 0][i]);
    o.y = bf16bits(tile[tx * 4 + 1][i]);
    o.z = bf16bits(tile[tx * 4 + 2][i]);
    o.w = bf16bits(tile[tx * 4 + 3][i]);
    *(ushort4*)&dstT[(size_t)(bx + i) * PDIM + by + tx * 4] = o;
  }
}

// ---- W_beta: fp8 cast + row-sum + scale[i] = W^2/(s*W^2+1) ----
__global__ void cast_wb_rows(const float* __restrict__ Wb,
                             unsigned char* __restrict__ Wb8,
                             const float* __restrict__ sAcc,
                             float* __restrict__ scale) {
  const size_t row = blockIdx.x;
  const float4* src = (const float4*)(Wb + row * PDIM);
  unsigned int* dst = (unsigned int*)(Wb8 + row * PDIM);
  float sum = 0.f;
#pragma unroll
  for (int it = 0; it < 4; ++it) {
    const int j = threadIdx.x + it * 256;
    const float4 v = src[j];
    sum += (v.x + v.y) + (v.z + v.w);
    dst[j] = fp8x4(v.x, v.y, v.z, v.w);
  }
#pragma unroll
  for (int off = 32; off > 0; off >>= 1) sum += __shfl_down(sum, off);
  __shared__ float ws[4];
  if ((threadIdx.x & 63) == 0) ws[threadIdx.x >> 6] = sum;
  __syncthreads();
  if (threadIdx.x == 0) {
    const float W = ws[0] + ws[1] + ws[2] + ws[3];
    const float w2 = W * W;
    scale[row] = w2 / ((*sAcc) * w2 + 1.0f);
  }
}

// ---- GEMM1: 256x256 tile, BK=64, 8-wave, read-ahead 4-phase pipeline ----
// Wm = scale[i] * (Y . X^T). outF fp32, Wm8 fp8 scaled by 2^17.
// Phase p: {stage half-tile of t+2 -> MFMA quadrant (operands pre-read) ->
// tail-read next quadrant's operands}. One barrier per phase.
// vmcnt(10)@P3 confirms Ah0(t+1); vmcnt(6)@P4 confirms all of t+1.
__device__ __forceinline__ void mfma_quad(floatx4 (&acc)[8][4], int mo, int no,
                                          const bf16x8 (&af)[8],
                                          const bf16x8 (&bf)[4]) {
  __builtin_amdgcn_s_setprio(1);
#pragma unroll
  for (int mi = 0; mi < 4; ++mi)
#pragma unroll
    for (int ni = 0; ni < 2; ++ni)
#pragma unroll
      for (int kk = 0; kk < 2; ++kk)
        acc[mo + mi][no + ni] = __builtin_amdgcn_mfma_f32_16x16x32_bf16(
            af[mi * 2 + kk], bf[ni * 2 + kk], acc[mo + mi][no + ni], 0, 0, 0);
  __builtin_amdgcn_s_setprio(0);
}

__device__ __forceinline__ void read_a(bf16x8 (&dst)[8], const char* base, int slot0) {
#pragma unroll
  for (int mi = 0; mi < 4; ++mi) {
    dst[mi * 2 + 0] = *(const bf16x8*)(base + mi * 2048 + slot0);
    dst[mi * 2 + 1] = *(const bf16x8*)(base + mi * 2048 + (slot0 ^ 64));
  }
}
__device__ __forceinline__ void read_b(bf16x8 (&dst)[4], const char* base, int slot0) {
#pragma unroll
  for (int ni = 0; ni < 2; ++ni) {
    dst[ni * 2 + 0] = *(const bf16x8*)(base + ni * 2048 + slot0);
    dst[ni * 2 + 1] = *(const bf16x8*)(base + ni * 2048 + (slot0 ^ 64));
  }
}

__global__ __launch_bounds__(512, 2)
void gemm_bf16_wm(const __hip_bfloat16* __restrict__ A,
                  const __hip_bfloat16* __restrict__ B,
                  const float* __restrict__ scale,
                  float* __restrict__ outF,
                  unsigned char* __restrict__ Wm8) {
  __shared__ __align__(16) char LDS[131072];

  const int tid = threadIdx.x;
  const int lane = tid & 63;
  const int wave = tid >> 6;
  const int wm = wave >> 2;
  const int wn = wave & 3;

  const int bid = blockIdx.x;
  const int swz = (bid & 7) * 32 + (bid >> 3);
  const int bx = swz & 15;
  const int by = swz >> 4;
  const size_t rowA0 = (size_t)by * 256;
  const size_t rowB0 = (size_t)bx * 256;

  const int srow = tid >> 3;
  const int scol = ((tid & 7) ^ (srow & 7)) << 4;
  const char* pA = (const char*)A + (rowA0 + srow) * 8192 + scol;
  const char* pB = (const char*)B + (rowB0 + srow) * 8192 + scol;
  const int ldsWav = wave * 1024;

  const int fr = lane & 15;
  const int kq = lane >> 4;
  const int slot0 = ((kq ^ (fr & 7)) << 4);
  const int aRowB = (wm * 64 + fr) * 128;
  const int bRowB = (wn * 32 + fr) * 128;

  floatx4 acc[8][4] = {};
  bf16x8 afLo[8], afHi[8], bLo[4], bHi[4];

  {
    char* dA0 = LDS + ldsWav;
    char* dB0 = LDS + 65536 + ldsWav;
    load_lds16(pA, dA0);                         load_lds16(pA + 524288, dA0 + 8192);
    load_lds16(pB, dB0);                         load_lds16(pB + 524288, dB0 + 8192);
    load_lds16(pB + 1048576, dB0 + 16384);       load_lds16(pB + 1572864, dB0 + 24576);
    load_lds16(pA + 1048576, dA0 + 16384);       load_lds16(pA + 1572864, dA0 + 24576);
    char* dA1 = dA0 + 32768;
    char* dB1 = dB0 + 32768;
    load_lds16(pA + 128, dA1);                   load_lds16(pA + 128 + 524288, dA1 + 8192);
    load_lds16(pB + 128, dB1);                   load_lds16(pB + 128 + 524288, dB1 + 8192);
    load_lds16(pB + 128 + 1048576, dB1 + 16384); load_lds16(pB + 128 + 1572864, dB1 + 24576);
    load_lds16(pA + 128 + 1048576, dA1 + 16384); load_lds16(pA + 128 + 1572864, dA1 + 24576);
  }
  asm volatile("s_waitcnt vmcnt(8)" ::: "memory");
  __builtin_amdgcn_s_barrier();
  read_a(afLo, (const char*)LDS + aRowB, slot0);
  read_b(bLo, (const char*)LDS + 65536 + bRowB, slot0);
  asm volatile("s_waitcnt lgkmcnt(0)" ::: "memory");
  __builtin_amdgcn_s_barrier();

  for (int t = 0; t < 64; ++t) {
    const int buf = (t & 1) << 15;
    const int tS = (t + 2) & 63;
    const char* sA = pA + (size_t)tS * 128;
    const char* sB = pB + (size_t)tS * 128;
    char* dA = LDS + buf + ldsWav;
    char* dB = LDS + 65536 + buf + ldsWav;
    const char* aRd  = LDS + buf + aRowB;
    const char* bRd  = LDS + 65536 + buf + bRowB;
    const char* aRdN = LDS + (buf ^ 32768) + aRowB;
    const char* bRdN = LDS + 65536 + (buf ^ 32768) + bRowB;

    // P1: stage Ah0(t+2); Q1 = MloNlo; tail-read bHi(t)
    load_lds16(sA, dA);
    load_lds16(sA + 524288, dA + 8192);
    mfma_quad(acc, 0, 0, afLo, bLo);
    read_b(bHi, bRd + 16384, slot0);
    __builtin_amdgcn_s_barrier();

    // P2: stage Bh0(t+2); Q2 = MloNhi; tail-read afHi(t)
    load_lds16(sB, dB);
    load_lds16(sB + 524288, dB + 8192);
    mfma_quad(acc, 0, 2, afLo, bHi);
    read_a(afHi, aRd + 16384, slot0);
    __builtin_amdgcn_s_barrier();

    // P3: vmcnt(10) confirms Ah0(t+1); stage Bh1(t+2); Q3; tail afLo(t+1)
    asm volatile("s_waitcnt vmcnt(10)" ::: "memory");
    load_lds16(sB + 1048576, dB + 16384);
    load_lds16(sB + 1572864, dB + 24576);
    mfma_quad(acc, 4, 2, afHi, bHi);
    read_a(afLo, aRdN, slot0);
    __builtin_amdgcn_s_barrier();

    // P4: vmcnt(6) confirms all t+1; stage Ah1(t+2); Q4; tail bLo(t+1)
    asm volatile("s_waitcnt vmcnt(6)" ::: "memory");
    load_lds16(sA + 1048576, dA + 16384);
    load_lds16(sA + 1572864, dA + 24576);
    mfma_quad(acc, 4, 0, afHi, bLo);
    read_b(bLo, bRdN, slot0);
    __builtin_amdgcn_s_barrier();
  }

  const int lr = (lane >> 4) << 2;
  const int lc = lane & 15;
#pragma unroll
  for (int mi = 0; mi < 8; ++mi) {
    const size_t rbase = rowA0 + (size_t)(mi >> 2) * 128 + wm * 64 + (mi & 3) * 16 + lr;
#pragma unroll
    for (int r = 0; r < 4; ++r) {
      const size_t row = rbase + r;
      const float sc = scale[row];
#pragma unroll
      for (int ni = 0; ni < 4; ++ni) {
        const size_t col = rowB0 + (size_t)(ni >> 1) * 128 + wn * 32 + (ni & 1) * 16 + lc;
        const float v = sc * acc[mi][ni][r];
        outF[row * PDIM + col] = v;
        Wm8[row * PDIM + col] = fp8byte(v * 131072.f);  // 2^17 pre-scale
      }
    }
  }
}

// ---- fp8 GEMMs: 256x256 tile, BK=128, 8-wave, read-ahead 4-phase pipeline ----
// Same schedule/swizzle/vmcnt accounting as gemm_bf16_wm (byte-identical tile
// geometry: 128 B/row K-step, 16KB half-tiles, 8 loads/tile).
// MODE 1: outP = fp8(acc*2^-17 - sub)   (P^T; B operand was pre-scaled 2^17)
// MODE 2: lossAcc += sum(acc^2)
union f8frag { int8v v; int4 h[2]; };

__device__ __forceinline__ void mfma_quad8(floatx4 (&acc)[8][4], int mo, int no,
                                           const f8frag (&af)[4],
                                           const f8frag (&bf)[2]) {
  __builtin_amdgcn_s_setprio(1);
#pragma unroll
  for (int mi = 0; mi < 4; ++mi)
#pragma unroll
    for (int ni = 0; ni < 2; ++ni)
      acc[mo + mi][no + ni] = __builtin_amdgcn_mfma_scale_f32_16x16x128_f8f6f4(
          af[mi].v, bf[ni].v, acc[mo + mi][no + ni],
          0 /*fp8*/, 0 /*fp8*/, 0, 0x7F7F7F7F, 0, 0x7F7F7F7F);
  __builtin_amdgcn_s_setprio(0);
}

__device__ __forceinline__ void read_a8(f8frag (&dst)[4], const char* base,
                                        int offLo, int offHi) {
#pragma unroll
  for (int mi = 0; mi < 4; ++mi) {
    dst[mi].h[0] = *(const int4*)(base + mi * 2048 + offLo);
    dst[mi].h[1] = *(const int4*)(base + mi * 2048 + offHi);
  }
}
__device__ __forceinline__ void read_b8(f8frag (&dst)[2], const char* base,
                                        int offLo, int offHi) {
#pragma unroll
  for (int ni = 0; ni < 2; ++ni) {
    dst[ni].h[0] = *(const int4*)(base + ni * 2048 + offLo);
    dst[ni].h[1] = *(const int4*)(base + ni * 2048 + offHi);
  }
}

template <int MODE>
__global__ __launch_bounds__(512, 2)
void gemm_fp8(const unsigned char* __restrict__ A,
              const unsigned char* __restrict__ B,
              const __hip_bfloat16* __restrict__ sub,
              unsigned char* __restrict__ outP,
              float* __restrict__ lossAcc) {
  __shared__ __align__(16) char LDS[131072];

  const int tid = threadIdx.x;
  const int lane = tid & 63;
  const int wave = tid >> 6;
  const int wm = wave >> 2;
  const int wn = wave & 3;

  const int bid = blockIdx.x;
  const int swz = (bid & 7) * 32 + (bid >> 3);
  const int bx = swz & 15;
  const int by = swz >> 4;
  const size_t rowA0 = (size_t)by * 256;
  const size_t rowB0 = (size_t)bx * 256;

  // staging: half-tile = 128 rows x 128 B; thread -> rows srow, srow+64
  const int srow = tid >> 3;
  const int scol = ((tid & 7) ^ (srow & 7)) << 4;
  const char* pA = (const char*)A + (rowA0 + srow) * 4096 + scol;
  const char* pB = (const char*)B + (rowB0 + srow) * 4096 + scol;
  const int ldsWav = wave * 1024;
  // global byte strides: 64 rows = 262144; half-tile (128 rows) = 524288

  // fragment read addressing (carried from verified 128^2 fp8 kernel)
  const int fr = lane & 15;
  const int e = fr & 7;
  const int q2 = (lane >> 4) << 1;
  const int offLo = (q2 ^ e) << 4;
  const int offHi = ((q2 + 1) ^ e) << 4;
  const int aRowB = (wm * 64 + fr) * 128;
  const int bRowB = (wn * 32 + fr) * 128;

  floatx4 acc[8][4] = {};
  f8frag afLo[4], afHi[4], bLo[2], bHi[2];

  // prologue: stage tiles 0,1 in order {Ah0,Bh0,Bh1,Ah1}
  {
    char* dA0 = LDS + ldsWav;
    char* dB0 = LDS + 65536 + ldsWav;
    load_lds16(pA, dA0);                        load_lds16(pA + 262144, dA0 + 8192);
    load_lds16(pB, dB0);                        load_lds16(pB + 262144, dB0 + 8192);
    load_lds16(pB + 524288, dB0 + 16384);       load_lds16(pB + 786432, dB0 + 24576);
    load_lds16(pA + 524288, dA0 + 16384);       load_lds16(pA + 786432, dA0 + 24576);
    char* dA1 = dA0 + 32768;
    char* dB1 = dB0 + 32768;
    load_lds16(pA + 128, dA1);                  load_lds16(pA + 128 + 262144, dA1 + 8192);
    load_lds16(pB + 128, dB1);                  load_lds16(pB + 128 + 262144, dB1 + 8192);
    load_lds16(pB + 128 + 524288, dB1 + 16384); load_lds16(pB + 128 + 786432, dB1 + 24576);
    load_lds16(pA + 128 + 524288, dA1 + 16384); load_lds16(pA + 128 + 786432, dA1 + 24576);
  }
  asm volatile("s_waitcnt vmcnt(8)" ::: "memory");
  __builtin_amdgcn_s_barrier();
  read_a8(afLo, (const char*)LDS + aRowB, offLo, offHi);
  read_b8(bLo, (const char*)LDS + 65536 + bRowB, offLo, offHi);
  asm volatile("s_waitcnt lgkmcnt(0)" ::: "memory");
  __builtin_amdgcn_s_barrier();

  for (int t = 0; t < 32; ++t) {
    const int buf = (t & 1) << 15;
    const int tS = (t + 2) & 31;
    const char* sA = pA + (size_t)tS * 128;
    const char* sB = pB + (size_t)tS * 128;
    char* dA = LDS + buf + ldsWav;
    char* dB = LDS + 65536 + buf + ldsWav;
    const char* aRd  = LDS + buf + aRowB;
    const char* bRd  = LDS + 65536 + buf + bRowB;
    const char* aRdN = LDS + (buf ^ 32768) + aRowB;
    const char* bRdN = LDS + 65536 + (buf ^ 32768) + bRowB;

    // P1: stage Ah0(t+2); Q1 = MloNlo; tail-read bHi(t)
    load_lds16(sA, dA);
    load_lds16(sA + 262144, dA + 8192);
    mfma_quad8(acc, 0, 0, afLo, bLo);
    read_b8(bHi, bRd + 16384, offLo, offHi);
    __builtin_amdgcn_s_barrier();

    // P2: stage Bh0(t+2); Q2 = MloNhi; tail-read afHi(t)
    load_lds16(sB, dB);
    load_lds16(sB + 262144, dB + 8192);
    mfma_quad8(acc, 0, 2, afLo, bHi);
    read_a8(afHi, aRd + 16384, offLo, offHi);
    __builtin_amdgcn_s_barrier();

    // P3: vmcnt(10) confirms Ah0(t+1); stage Bh1(t+2); Q3; tail afLo(t+1)
    asm volatile("s_waitcnt vmcnt(10)" ::: "memory");
    load_lds16(sB + 524288, dB + 16384);
    load_lds16(sB + 786432, dB + 24576);
    mfma_quad8(acc, 4, 2, afHi, bHi);
    read_a8(afLo, aRdN, offLo, offHi);
    __builtin_amdgcn_s_barrier();

    // P4: vmcnt(6) confirms all t+1; stage Ah1(t+2); Q4; tail bLo(t+1)
    asm volatile("s_waitcnt vmcnt(6)" ::: "memory");
    load_lds16(sA + 524288, dA + 16384);
    load_lds16(sA + 786432, dA + 24576);
    mfma_quad8(acc, 4, 0, afHi, bLo);
    read_b8(bLo, bRdN, offLo, offHi);
    __builtin_amdgcn_s_barrier();
  }

  const int lr = (lane >> 4) << 2;
  const int lc = lane & 15;

  if constexpr (MODE == 2) {
    float tot = 0.f;
#pragma unroll
    for (int mi = 0; mi < 8; ++mi)
#pragma unroll
      for (int ni = 0; ni < 4; ++ni)
#pragma unroll
        for (int r = 0; r < 4; ++r) tot += acc[mi][ni][r] * acc[mi][ni][r];
#pragma unroll
    for (int off = 32; off > 0; off >>= 1) tot += __shfl_down(tot, off);
    __shared__ float ws[8];
    if (lane == 0) ws[wave] = tot;
    __syncthreads();
    if (tid == 0)
      atomicAdd(lossAcc, ws[0] + ws[1] + ws[2] + ws[3] + ws[4] + ws[5] + ws[6] + ws[7]);
  } else {
    constexpr float INV = 1.f / 131072.f;
#pragma unroll
    for (int mi = 0; mi < 8; ++mi) {
      const size_t rbase = rowA0 + (size_t)(mi >> 2) * 128 + wm * 64 + (mi & 3) * 16 + lr;
#pragma unroll
      for (int r = 0; r < 4; ++r) {
        const size_t row = rbase + r;
#pragma unroll
        for (int ni = 0; ni < 4; ++ni) {
          const size_t col = rowB0 + (size_t)(ni >> 1) * 128 + wn * 32 + (ni & 1) * 16 + lc;
          const float v = acc[mi][ni][r] * INV - __bfloat162float(sub[row * PDIM + col]);
          outP[row * PDIM + col] = fp8byte(v);
        }
      }
    }
  }
}

__global__ void finalize(float* __restrict__ out, const float* __restrict__ acc) {
  if (threadIdx.x == 0) out[0] = sqrtf(*acc);
}

extern "C" void kernel_launch(void* const* d_in, const int* in_sizes, int n_in,
                              void* d_out, int out_size, void* d_ws, size_t ws_size,
                              hipStream_t stream) {
  const float* X  = (const float*)d_in[0];
  const float* Y  = (const float*)d_in[1];
  const float* Wb = (const float*)d_in[2];
  float* out = (float*)d_out;  // [0]=loss, [1..]=W_matrix (fp32)

  // workspace: 3x bf16 (32MB) + 4x fp8 (16MB) = 160MB + small
  __hip_bfloat16* Xb   = (__hip_bfloat16*)d_ws;           // X bf16   (GEMM1 B)
  __hip_bfloat16* Yb   = Xb + PPN;                        // Y bf16   (GEMM1 A)
  __hip_bfloat16* YbT  = Yb + PPN;                        // Y^T bf16 (GEMM2 epi)
  unsigned char*  XT8  = (unsigned char*)(YbT + PPN);     // X^T fp8  (GEMM2 A)
  unsigned char*  Wm8  = XT8 + PPN;                       // Wm*2^17 fp8 (GEMM2 B)
  unsigned char*  Wb8  = Wm8 + PPN;                       // W_beta fp8 (GEMM3 B)
  unsigned char*  PT8  = Wb8 + PPN;                       // P^T fp8  (GEMM3 A)
  float* scale   = (float*)(PT8 + PPN);                   // [4096]
  float* sAcc    = scale + PDIM;
  float* lossAcc = sAcc + 1;

  hipMemsetAsync(sAcc, 0, 2 * sizeof(float), stream);

  sumsq<<<1024, 256, 0, stream>>>((const float4*)X, sAcc);

  dim3 cgrid(PDIM / 64, PDIM / 64);
  cast_x<<<cgrid, 256, 0, stream>>>(X, Xb, XT8);
  cast_y<<<cgrid, 256, 0, stream>>>(Y, Yb, YbT);
  cast_wb_rows<<<PDIM, 256, 0, stream>>>(Wb, Wb8, sAcc, scale);

  // GEMM1 (bf16, 256^2 read-ahead pipeline): Wm = scale[i]*Y.X^T -> out+1, Wm8
  gemm_bf16_wm<<<dim3(256), 512, 0, stream>>>(Yb, Xb, scale, out + 1, Wm8);

  // GEMM2 (fp8, 256^2 pipeline): PT[b,a] = (XT.Wm8^T)*2^-17 - YT -> PT8
  gemm_fp8<1><<<dim3(256), 512, 0, stream>>>(XT8, Wm8, YbT, PT8, nullptr);
  // GEMM3 (fp8, 256^2 pipeline): lossAcc += ||Wb.P||_F^2
  gemm_fp8<2><<<dim3(256), 512, 0, stream>>>(PT8, Wb8, nullptr, nullptr, lossAcc);

  finalize<<<1, 1, 0, stream>>>(out, lossAcc);
}